// Round 2
// baseline (43829.025 us; speedup 1.0000x reference)
//
#include <hip/hip_runtime.h>
#include <math.h>

#define VIS 1024
#define HID 1024
#define NROW 8192
#define KDIM 2048
#define NDIM 2048
#define NSTEPS 2010
#define KLS 10
#define NWG 64
#define COLS 16   // columns per gibbs WG

// ---- ws layout (bytes) ----
#define WT_OFF   0u                      // wT: 1024x1024 f32 (4 MB)
#define LP_OFF   4194304u                // lp_row: 8192 f32
#define FE_OFF   (LP_OFF + 32768u)       // fe_row: 8192 f32
#define FES_OFF  (FE_OFF + 32768u)       // fe_samples sum: 1 double
#define ZERO_BYTES (FES_OFF + 8u - LP_OFF)
#define SVW_OFF  (FES_OFF + 64u)         // sv words: 1024 u32
#define SHW_OFF  (SVW_OFF + 4096u)       // sh words: 1024 u32
#define SSV_OFF  (SHW_OFF + 4096u)       // samples sv: 10x1024 f32
#define SSH_OFF  (SSV_OFF + 40960u)      // samples sh: 10x1024 f32

__global__ __launch_bounds__(256) void init_zero(float* p, int n) {
    int i = blockIdx.x * 256 + threadIdx.x;
    if (i < n) p[i] = 0.f;
}

__global__ __launch_bounds__(256) void init_words(const float* __restrict__ u_init,
                                                  unsigned int* __restrict__ svw,
                                                  unsigned int* __restrict__ shw) {
    int i = blockIdx.x * 256 + threadIdx.x;
    if (i < 1024) {
        svw[i] = (u_init[i] >= 0.5f) ? 1u : 0u;  // tag 0 | bit
        shw[i] = 0xFFFFFFFFu;                    // never matches any expected tag
    }
}

__global__ __launch_bounds__(256) void transpose_w_k(const float* __restrict__ w,
                                                     float* __restrict__ wT) {
    __shared__ float tile[32][33];
    int bx = blockIdx.x * 32, by = blockIdx.y * 32;
    int tx = threadIdx.x & 31, ty = threadIdx.x >> 5;  // ty 0..7
    #pragma unroll
    for (int m = 0; m < 4; ++m) {
        int y = by + ty + m * 8;
        tile[ty + m * 8][tx] = w[(size_t)y * 1024 + bx + tx];
    }
    __syncthreads();
    #pragma unroll
    for (int m = 0; m < 4; ++m) {
        int y = bx + ty + m * 8;
        wT[(size_t)y * 1024 + by + tx] = tile[tx][ty + m * 8];
    }
}

// ---------- GEMM1: logits = vecs@lw + lb ; fused zeta + log-posterior ----------
#define BM 128
#define BN 128
#define BK 8

__global__ __launch_bounds__(256) void gemm1_zeta_lp(
    const float* __restrict__ A, const float* __restrict__ B,
    const float* __restrict__ lb, const float* __restrict__ eps,
    const float* __restrict__ bv, const float* __restrict__ bh,
    float* __restrict__ zv, float* __restrict__ zh, float* __restrict__ lp_row)
{
    __shared__ float As[BK][BM];
    __shared__ float Bs[BK][BN];
    __shared__ float red[BM * 16];
    const int tid = threadIdx.x;
    const int n0 = blockIdx.x * BN;
    const int m0 = blockIdx.y * BM;
    const int tx = tid & 15, ty = tid >> 4;
    const int ar = tid >> 1, ac = (tid & 1) * 4;
    const int br = tid >> 5, bc = (tid & 31) * 4;

    float acc[8][8];
    #pragma unroll
    for (int i = 0; i < 8; ++i)
        #pragma unroll
        for (int j = 0; j < 8; ++j) acc[i][j] = 0.f;

    for (int k0 = 0; k0 < KDIM; k0 += BK) {
        float4 a = *reinterpret_cast<const float4*>(&A[(size_t)(m0 + ar) * KDIM + k0 + ac]);
        float4 b = *reinterpret_cast<const float4*>(&B[(size_t)(k0 + br) * NDIM + n0 + bc]);
        __syncthreads();
        As[ac + 0][ar] = a.x; As[ac + 1][ar] = a.y; As[ac + 2][ar] = a.z; As[ac + 3][ar] = a.w;
        *reinterpret_cast<float4*>(&Bs[br][bc]) = b;
        __syncthreads();
        #pragma unroll
        for (int k = 0; k < BK; ++k) {
            float av[8], bw[8];
            const float4* ap = reinterpret_cast<const float4*>(&As[k][ty * 8]);
            const float4* bp = reinterpret_cast<const float4*>(&Bs[k][tx * 8]);
            float4 a0 = ap[0], a1 = ap[1], b0 = bp[0], b1 = bp[1];
            av[0]=a0.x; av[1]=a0.y; av[2]=a0.z; av[3]=a0.w; av[4]=a1.x; av[5]=a1.y; av[6]=a1.z; av[7]=a1.w;
            bw[0]=b0.x; bw[1]=b0.y; bw[2]=b0.z; bw[3]=b0.w; bw[4]=b1.x; bw[5]=b1.y; bw[6]=b1.z; bw[7]=b1.w;
            #pragma unroll
            for (int i = 0; i < 8; ++i)
                #pragma unroll
                for (int j = 0; j < 8; ++j)
                    acc[i][j] = fmaf(av[i], bw[j], acc[i][j]);
        }
    }

    const bool isv = (n0 < VIS);
    float lpacc[8];
    #pragma unroll
    for (int i = 0; i < 8; ++i) {
        const int row = m0 + ty * 8 + i;
        float s = 0.f;
        #pragma unroll
        for (int j = 0; j < 8; ++j) {
            const int n = n0 + tx * 8 + j;
            float l = acc[i][j] + lb[n];
            float e = eps[(size_t)row * NDIM + n];
            float z = 1.f / (1.f + expf(-(l + e) * 5.f));
            float p = 1.f / (1.f + expf(-l));
            float bb;
            if (isv) { zv[(size_t)row * VIS + n] = z; bb = bv[n]; }
            else     { zh[(size_t)row * HID + (n - VIS)] = z; bb = bh[n - VIS]; }
            s += logf(z * p + (1.f - z) * (1.f - p)) + z * bb;
        }
        lpacc[i] = s;
    }
    __syncthreads();
    #pragma unroll
    for (int i = 0; i < 8; ++i) red[(ty * 8 + i) * 16 + tx] = lpacc[i];
    __syncthreads();
    if (tid < BM) {
        float s = 0.f;
        #pragma unroll
        for (int x = 0; x < 16; ++x) s += red[tid * 16 + x];
        atomicAdd(&lp_row[m0 + tid], s);
    }
}

// ---------- GEMM2: fe quadratic term: rowsum((zeta_v @ w) * zeta_h) ----------
__global__ __launch_bounds__(256) void gemm2_fe(
    const float* __restrict__ A, const float* __restrict__ B,
    const float* __restrict__ ZH, float* __restrict__ fe_row)
{
    __shared__ float As[BK][BM];
    __shared__ float Bs[BK][BN];
    __shared__ float red[BM * 16];
    const int tid = threadIdx.x;
    const int n0 = blockIdx.x * BN;
    const int m0 = blockIdx.y * BM;
    const int tx = tid & 15, ty = tid >> 4;
    const int ar = tid >> 1, ac = (tid & 1) * 4;
    const int br = tid >> 5, bc = (tid & 31) * 4;

    float acc[8][8];
    #pragma unroll
    for (int i = 0; i < 8; ++i)
        #pragma unroll
        for (int j = 0; j < 8; ++j) acc[i][j] = 0.f;

    for (int k0 = 0; k0 < 1024; k0 += BK) {
        float4 a = *reinterpret_cast<const float4*>(&A[(size_t)(m0 + ar) * 1024 + k0 + ac]);
        float4 b = *reinterpret_cast<const float4*>(&B[(size_t)(k0 + br) * 1024 + n0 + bc]);
        __syncthreads();
        As[ac + 0][ar] = a.x; As[ac + 1][ar] = a.y; As[ac + 2][ar] = a.z; As[ac + 3][ar] = a.w;
        *reinterpret_cast<float4*>(&Bs[br][bc]) = b;
        __syncthreads();
        #pragma unroll
        for (int k = 0; k < BK; ++k) {
            float av[8], bw[8];
            const float4* ap = reinterpret_cast<const float4*>(&As[k][ty * 8]);
            const float4* bp = reinterpret_cast<const float4*>(&Bs[k][tx * 8]);
            float4 a0 = ap[0], a1 = ap[1], b0 = bp[0], b1 = bp[1];
            av[0]=a0.x; av[1]=a0.y; av[2]=a0.z; av[3]=a0.w; av[4]=a1.x; av[5]=a1.y; av[6]=a1.z; av[7]=a1.w;
            bw[0]=b0.x; bw[1]=b0.y; bw[2]=b0.z; bw[3]=b0.w; bw[4]=b1.x; bw[5]=b1.y; bw[6]=b1.z; bw[7]=b1.w;
            #pragma unroll
            for (int i = 0; i < 8; ++i)
                #pragma unroll
                for (int j = 0; j < 8; ++j)
                    acc[i][j] = fmaf(av[i], bw[j], acc[i][j]);
        }
    }

    float feacc[8];
    #pragma unroll
    for (int i = 0; i < 8; ++i) {
        const int row = m0 + ty * 8 + i;
        float s = 0.f;
        #pragma unroll
        for (int j = 0; j < 8; ++j) {
            const int n = n0 + tx * 8 + j;
            s += acc[i][j] * ZH[(size_t)row * HID + n];
        }
        feacc[i] = s;
    }
    __syncthreads();
    #pragma unroll
    for (int i = 0; i < 8; ++i) red[(ty * 8 + i) * 16 + tx] = feacc[i];
    __syncthreads();
    if (tid < BM) {
        float s = 0.f;
        #pragma unroll
        for (int x = 0; x < 16; ++x) s += red[tid * 16 + x];
        atomicAdd(&fe_row[m0 + tid], s);
    }
}

// ---------- Gibbs chain v2: version-tagged words, relaxed atomics, no fences ----
// word = (tag<<1)|bit. sv tag t = state entering step t's phase a (init tag 0,
// phase b of step t writes tag t+1). sh tag t+1 = output of phase a of step t.
// Single-buffer is skew-1 safe: a writer can only reach tag t+1 after every
// reader consumed tag t (enforced by the data dependency chain itself).
__global__ __launch_bounds__(256) void gibbs_k(
    const float* __restrict__ w, const float* __restrict__ wT,
    const float* __restrict__ bv, const float* __restrict__ bh,
    const float* __restrict__ u_h, const float* __restrict__ u_v,
    unsigned int* __restrict__ svw, unsigned int* __restrict__ shw,
    float* __restrict__ ssv, float* __restrict__ ssh)
{
    __shared__ unsigned int sbits[1024];
    __shared__ double red[16][16];
    const int tid = threadIdx.x;
    const int k = blockIdx.x;
    const int c = tid & 15;
    const int r = tid >> 4;              // 0..15
    const int col = k * COLS + c;

    for (int t = 0; t < NSTEPS; ++t) {
        // ================= phase a: sh = bern(uh, sigmoid(bh + sv@w)) =========
        // decision u >= sigmoid(y)  <=>  dot <= logit(u) - b ; compute the f64
        // threshold BEFORE polling so log latency hides under the wait.
        double th = 0.0;
        if (r == 0) {
            double u = (double)u_h[(size_t)t * 1024 + col];
            th = log(u) - log1p(-u) - (double)bh[col];
        }
        {
            const unsigned int expect = (unsigned int)t;
            unsigned int v0, v1, v2, v3;
            for (;;) {
                v0 = __hip_atomic_load(&svw[tid      ], __ATOMIC_RELAXED, __HIP_MEMORY_SCOPE_AGENT);
                v1 = __hip_atomic_load(&svw[tid + 256], __ATOMIC_RELAXED, __HIP_MEMORY_SCOPE_AGENT);
                v2 = __hip_atomic_load(&svw[tid + 512], __ATOMIC_RELAXED, __HIP_MEMORY_SCOPE_AGENT);
                v3 = __hip_atomic_load(&svw[tid + 768], __ATOMIC_RELAXED, __HIP_MEMORY_SCOPE_AGENT);
                if (((v0 >> 1) == expect) & ((v1 >> 1) == expect) &
                    ((v2 >> 1) == expect) & ((v3 >> 1) == expect)) break;
            }
            sbits[tid      ] = v0 & 1u;
            sbits[tid + 256] = v1 & 1u;
            sbits[tid + 512] = v2 & 1u;
            sbits[tid + 768] = v3 & 1u;
        }
        __syncthreads();                                  // S1: sbits ready
        {
            double y0 = 0.0, y1 = 0.0;
            #pragma unroll 8
            for (int i = r; i < 1024; i += 32) {
                if (sbits[i])      y0 += (double)w[(size_t)i * 1024 + col];
                if (sbits[i + 16]) y1 += (double)w[(size_t)(i + 16) * 1024 + col];
            }
            red[r][c] = y0 + y1;
        }
        __syncthreads();                                  // S2: red ready
        if (r == 0) {
            double yy = red[0][c];
            #pragma unroll
            for (int q = 1; q < 16; ++q) yy += red[q][c];
            unsigned int bit = (yy <= th) ? 1u : 0u;
            __hip_atomic_store(&shw[col], (((unsigned int)(t + 1)) << 1) | bit,
                               __ATOMIC_RELAXED, __HIP_MEMORY_SCOPE_AGENT);
            if (t >= NSTEPS - KLS)
                ssh[(size_t)(t - (NSTEPS - KLS)) * 1024 + col] = (float)bit;
        }

        // ================= phase b: sv2 = bern(uv, sigmoid(bv + sh@wT)) =======
        double tv = 0.0;
        if (r == 0) {
            double u = (double)u_v[(size_t)t * 1024 + col];
            tv = log(u) - log1p(-u) - (double)bv[col];
        }
        {
            const unsigned int expect = (unsigned int)(t + 1);
            unsigned int v0, v1, v2, v3;
            for (;;) {
                v0 = __hip_atomic_load(&shw[tid      ], __ATOMIC_RELAXED, __HIP_MEMORY_SCOPE_AGENT);
                v1 = __hip_atomic_load(&shw[tid + 256], __ATOMIC_RELAXED, __HIP_MEMORY_SCOPE_AGENT);
                v2 = __hip_atomic_load(&shw[tid + 512], __ATOMIC_RELAXED, __HIP_MEMORY_SCOPE_AGENT);
                v3 = __hip_atomic_load(&shw[tid + 768], __ATOMIC_RELAXED, __HIP_MEMORY_SCOPE_AGENT);
                if (((v0 >> 1) == expect) & ((v1 >> 1) == expect) &
                    ((v2 >> 1) == expect) & ((v3 >> 1) == expect)) break;
            }
            sbits[tid      ] = v0 & 1u;
            sbits[tid + 256] = v1 & 1u;
            sbits[tid + 512] = v2 & 1u;
            sbits[tid + 768] = v3 & 1u;
        }
        __syncthreads();                                  // S1
        {
            double y0 = 0.0, y1 = 0.0;
            #pragma unroll 8
            for (int j = r; j < 1024; j += 32) {
                if (sbits[j])      y0 += (double)wT[(size_t)j * 1024 + col];
                if (sbits[j + 16]) y1 += (double)wT[(size_t)(j + 16) * 1024 + col];
            }
            red[r][c] = y0 + y1;
        }
        __syncthreads();                                  // S2
        if (r == 0) {
            double yy = red[0][c];
            #pragma unroll
            for (int q = 1; q < 16; ++q) yy += red[q][c];
            unsigned int bit = (yy <= tv) ? 1u : 0u;
            __hip_atomic_store(&svw[col], (((unsigned int)(t + 1)) << 1) | bit,
                               __ATOMIC_RELAXED, __HIP_MEMORY_SCOPE_AGENT);
            if (t >= NSTEPS - KLS)
                ssv[(size_t)(t - (NSTEPS - KLS)) * 1024 + col] = (float)bit;
        }
    }
}

// ---------- free energy of the 10 samples (f64) ----------
__global__ __launch_bounds__(256) void fe_samples_k(
    const float* __restrict__ w, const float* __restrict__ bv,
    const float* __restrict__ bh, const float* __restrict__ ssv,
    const float* __restrict__ ssh, double* __restrict__ fe_sum)
{
    __shared__ float svl[1024], shl[1024];
    __shared__ double dred[256];
    const int s = blockIdx.x, tid = threadIdx.x;
    for (int m = tid; m < 1024; m += 256) {
        svl[m] = ssv[(size_t)s * 1024 + m];
        shl[m] = ssh[(size_t)s * 1024 + m];
    }
    __syncthreads();
    double acc = 0.0;
    for (int jj = 0; jj < 4; ++jj) {
        int j = tid + jj * 256;
        acc += (double)(svl[j] * bv[j]) + (double)(shl[j] * bh[j]);
        if (shl[j] != 0.f) {
            double y = 0.0;
            for (int i = 0; i < 1024; ++i)
                if (svl[i] != 0.f) y += (double)w[(size_t)i * 1024 + j];
            acc += y;
        }
    }
    dred[tid] = acc;
    __syncthreads();
    for (int off = 128; off > 0; off >>= 1) {
        if (tid < off) dred[tid] += dred[tid + off];
        __syncthreads();
    }
    if (tid == 0) atomicAdd(fe_sum, dred[0]);
}

__global__ __launch_bounds__(256) void final_kl(
    const float* __restrict__ lp_row, const float* __restrict__ fe_row,
    const double* __restrict__ fe_sum, float* __restrict__ out_kl)
{
    __shared__ double dred[256];
    const int tid = threadIdx.x;
    double acc = 0.0;
    for (int r = tid; r < NROW; r += 256)
        acc += (double)lp_row[r] + (double)fe_row[r];
    dred[tid] = acc;
    __syncthreads();
    for (int off = 128; off > 0; off >>= 1) {
        if (tid < off) dred[tid] += dred[tid + off];
        __syncthreads();
    }
    if (tid == 0) out_kl[0] = (float)(dred[0] / 8192.0 - fe_sum[0] / 10.0);
}

extern "C" void kernel_launch(void* const* d_in, const int* in_sizes, int n_in,
                              void* d_out, int out_size, void* d_ws, size_t ws_size,
                              hipStream_t stream)
{
    const float* vecs   = (const float*)d_in[0];
    const float* lw     = (const float*)d_in[1];
    const float* lb     = (const float*)d_in[2];
    const float* w      = (const float*)d_in[3];
    const float* bv     = (const float*)d_in[4];
    const float* bh     = (const float*)d_in[5];
    const float* eps    = (const float*)d_in[6];
    const float* u_init = (const float*)d_in[7];
    const float* u_h    = (const float*)d_in[8];
    const float* u_v    = (const float*)d_in[9];

    float* out    = (float*)d_out;
    float* zv     = out;
    float* zh     = out + (size_t)NROW * VIS;
    float* out_kl = out + (size_t)NROW * 2048;

    char* ws = (char*)d_ws;
    float*        wT     = (float*)(ws + WT_OFF);
    float*        lp_row = (float*)(ws + LP_OFF);
    float*        fe_row = (float*)(ws + FE_OFF);
    double*       fes    = (double*)(ws + FES_OFF);
    unsigned int* svw    = (unsigned int*)(ws + SVW_OFF);
    unsigned int* shw    = (unsigned int*)(ws + SHW_OFF);
    float*        ssv    = (float*)(ws + SSV_OFF);
    float*        ssh    = (float*)(ws + SSH_OFF);

    const int zwords = (int)(ZERO_BYTES / 4);
    init_zero<<<(zwords + 255) / 256, 256, 0, stream>>>(lp_row, zwords);
    init_words<<<4, 256, 0, stream>>>(u_init, svw, shw);
    transpose_w_k<<<dim3(32, 32), 256, 0, stream>>>(w, wT);
    gemm1_zeta_lp<<<dim3(16, 64), 256, 0, stream>>>(vecs, lw, lb, eps, bv, bh, zv, zh, lp_row);
    gemm2_fe<<<dim3(8, 64), 256, 0, stream>>>(zv, w, zh, fe_row);
    gibbs_k<<<NWG, 256, 0, stream>>>(w, wT, bv, bh, u_h, u_v, svw, shw, ssv, ssh);
    fe_samples_k<<<KLS, 256, 0, stream>>>(w, bv, bh, ssv, ssh, fes);
    final_kl<<<1, 256, 0, stream>>>(lp_row, fe_row, fes, out_kl);
}

// Round 3
// 41406.464 us; speedup vs baseline: 1.0585x; 1.0585x over previous
//
#include <hip/hip_runtime.h>
#include <math.h>

#define VIS 1024
#define HID 1024
#define NROW 8192
#define KDIM 2048
#define NDIM 2048
#define NSTEPS 2010
#define KLS 10
#define NWG 64
#define COLS 16   // columns per gibbs WG

// ---- ws layout (bytes) ----
#define WT_OFF   0u                      // wT: 1024x1024 f32 (4 MB)
#define LP_OFF   4194304u                // lp_row: 8192 f32
#define FE_OFF   (LP_OFF + 32768u)       // fe_row: 8192 f32
#define FES_OFF  (FE_OFF + 32768u)       // fe_samples sum: 1 double
#define ZERO_BYTES (FES_OFF + 8u - LP_OFF)
#define PUBV_OFF (FES_OFF + 64u)         // pubV: 64 words @ 64B stride (4 KB)
#define PUBH_OFF (PUBV_OFF + 4096u)      // pubH: 64 words @ 64B stride (4 KB)
#define SSV_OFF  (PUBH_OFF + 4096u)      // samples sv: 10x1024 f32
#define SSH_OFF  (SSV_OFF + 40960u)      // samples sh: 10x1024 f32

__global__ __launch_bounds__(256) void init_zero(float* p, int n) {
    int i = blockIdx.x * 256 + threadIdx.x;
    if (i < n) p[i] = 0.f;
}

// one u32 per WG: (tag<<16)|bits16. pubV tag0 = init state; pubH tag 0xFFFF = never-match.
__global__ __launch_bounds__(64) void init_words(const float* __restrict__ u_init,
                                                 unsigned int* __restrict__ pubV,
                                                 unsigned int* __restrict__ pubH) {
    int i = threadIdx.x;  // 0..63
    unsigned int bits = 0u;
    #pragma unroll
    for (int j = 0; j < 16; ++j)
        bits |= ((u_init[i * 16 + j] >= 0.5f) ? 1u : 0u) << j;
    pubV[i * 16] = bits;           // tag 0 | bits
    pubH[i * 16] = 0xFFFF0000u;    // tag 0xFFFF never expected
}

__global__ __launch_bounds__(256) void transpose_w_k(const float* __restrict__ w,
                                                     float* __restrict__ wT) {
    __shared__ float tile[32][33];
    int bx = blockIdx.x * 32, by = blockIdx.y * 32;
    int tx = threadIdx.x & 31, ty = threadIdx.x >> 5;  // ty 0..7
    #pragma unroll
    for (int m = 0; m < 4; ++m) {
        int y = by + ty + m * 8;
        tile[ty + m * 8][tx] = w[(size_t)y * 1024 + bx + tx];
    }
    __syncthreads();
    #pragma unroll
    for (int m = 0; m < 4; ++m) {
        int y = bx + ty + m * 8;
        wT[(size_t)y * 1024 + by + tx] = tile[tx][ty + m * 8];
    }
}

#define BM 128
#define BN 128
#define BK 8

struct SGibbs {
    unsigned int words[64];
    double red[16][16];
};
struct SMm {
    float As[BK][BM];
    float Bs[BK][BN];
    float red[BM * 16];
};
union SharedU {
    SGibbs g;
    SMm m;
};

// ---------- fused: blocks [0,64) = gibbs chain; blocks [64,1088) = GEMM1 -------
__global__ __launch_bounds__(256) void gibbs_gemm1_k(
    const float* __restrict__ w, const float* __restrict__ wT,
    const float* __restrict__ bv, const float* __restrict__ bh,
    const float* __restrict__ u_h, const float* __restrict__ u_v,
    unsigned int* __restrict__ pubV, unsigned int* __restrict__ pubH,
    float* __restrict__ ssv, float* __restrict__ ssh,
    const float* __restrict__ A, const float* __restrict__ B,
    const float* __restrict__ lb, const float* __restrict__ eps,
    float* __restrict__ zv, float* __restrict__ zh, float* __restrict__ lp_row)
{
    __shared__ SharedU su;
    const int tid = threadIdx.x;

    if (blockIdx.x < NWG) {
        // ======================= GIBBS =======================
        const int k = blockIdx.x;
        const int c = tid & 15;
        const int r = tid >> 4;              // 0..15
        const int col = k * COLS + c;

        for (int t = 0; t < NSTEPS; ++t) {
            // ---- phase a: sh = bern(uh, sigmoid(bh + sv@w)) ----
            // decision u >= sigmoid(y) <=> dot <= logit(u) - b
            double th = 0.0;
            if (r == 0) {
                double u = (double)u_h[(size_t)t * 1024 + col];
                th = log(u) - log1p(-u) - (double)bh[col];
            }
            if (tid < 64) {
                unsigned int v;
                do {
                    v = __hip_atomic_load(&pubV[tid * 16], __ATOMIC_RELAXED,
                                          __HIP_MEMORY_SCOPE_AGENT);
                } while ((v >> 16) != (unsigned int)t);
                su.g.words[tid] = v & 0xFFFFu;
            }
            __syncthreads();                                  // S1: words ready
            {
                double y0 = 0.0, y1 = 0.0;
                #pragma unroll 4
                for (int m = 0; m < 32; ++m) {
                    unsigned int w0 = su.g.words[2 * m];
                    unsigned int w1 = su.g.words[2 * m + 1];
                    int i0 = 32 * m + r;
                    if ((w0 >> r) & 1u) y0 += (double)w[(size_t)i0 * 1024 + col];
                    if ((w1 >> r) & 1u) y1 += (double)w[(size_t)(i0 + 16) * 1024 + col];
                }
                su.g.red[r][c] = y0 + y1;
            }
            __syncthreads();                                  // S2: red ready
            bool pb = false;
            if (r == 0) {
                double yy = su.g.red[0][c];
                #pragma unroll
                for (int q = 1; q < 16; ++q) yy += su.g.red[q][c];
                pb = (yy <= th);
                if (t >= NSTEPS - KLS)
                    ssh[(size_t)(t - (NSTEPS - KLS)) * 1024 + col] = pb ? 1.f : 0.f;
            }
            unsigned long long bal = __ballot(pb);
            if (tid == 0)
                __hip_atomic_store(&pubH[k * 16],
                                   (((unsigned int)(t + 1)) << 16) | ((unsigned int)bal & 0xFFFFu),
                                   __ATOMIC_RELAXED, __HIP_MEMORY_SCOPE_AGENT);

            // ---- phase b: sv2 = bern(uv, sigmoid(bv + sh@wT)) ----
            double tv = 0.0;
            if (r == 0) {
                double u = (double)u_v[(size_t)t * 1024 + col];
                tv = log(u) - log1p(-u) - (double)bv[col];
            }
            if (tid < 64) {
                unsigned int v;
                do {
                    v = __hip_atomic_load(&pubH[tid * 16], __ATOMIC_RELAXED,
                                          __HIP_MEMORY_SCOPE_AGENT);
                } while ((v >> 16) != (unsigned int)(t + 1));
                su.g.words[tid] = v & 0xFFFFu;
            }
            __syncthreads();                                  // S1
            {
                double y0 = 0.0, y1 = 0.0;
                #pragma unroll 4
                for (int m = 0; m < 32; ++m) {
                    unsigned int w0 = su.g.words[2 * m];
                    unsigned int w1 = su.g.words[2 * m + 1];
                    int j0 = 32 * m + r;
                    if ((w0 >> r) & 1u) y0 += (double)wT[(size_t)j0 * 1024 + col];
                    if ((w1 >> r) & 1u) y1 += (double)wT[(size_t)(j0 + 16) * 1024 + col];
                }
                su.g.red[r][c] = y0 + y1;
            }
            __syncthreads();                                  // S2
            pb = false;
            if (r == 0) {
                double yy = su.g.red[0][c];
                #pragma unroll
                for (int q = 1; q < 16; ++q) yy += su.g.red[q][c];
                pb = (yy <= tv);
                if (t >= NSTEPS - KLS)
                    ssv[(size_t)(t - (NSTEPS - KLS)) * 1024 + col] = pb ? 1.f : 0.f;
            }
            bal = __ballot(pb);
            if (tid == 0)
                __hip_atomic_store(&pubV[k * 16],
                                   (((unsigned int)(t + 1)) << 16) | ((unsigned int)bal & 0xFFFFu),
                                   __ATOMIC_RELAXED, __HIP_MEMORY_SCOPE_AGENT);
        }
        return;
    }

    // ======================= GEMM1 (+ zeta + log-posterior) =======================
    const int gid = blockIdx.x - NWG;
    const int n0 = (gid & 15) * BN;
    const int m0 = (gid >> 4) * BM;
    const int tx = tid & 15, ty = tid >> 4;
    const int ar = tid >> 1, ac = (tid & 1) * 4;
    const int br = tid >> 5, bc = (tid & 31) * 4;

    float acc[8][8];
    #pragma unroll
    for (int i = 0; i < 8; ++i)
        #pragma unroll
        for (int j = 0; j < 8; ++j) acc[i][j] = 0.f;

    for (int k0 = 0; k0 < KDIM; k0 += BK) {
        float4 a = *reinterpret_cast<const float4*>(&A[(size_t)(m0 + ar) * KDIM + k0 + ac]);
        float4 b = *reinterpret_cast<const float4*>(&B[(size_t)(k0 + br) * NDIM + n0 + bc]);
        __syncthreads();
        su.m.As[ac + 0][ar] = a.x; su.m.As[ac + 1][ar] = a.y;
        su.m.As[ac + 2][ar] = a.z; su.m.As[ac + 3][ar] = a.w;
        *reinterpret_cast<float4*>(&su.m.Bs[br][bc]) = b;
        __syncthreads();
        #pragma unroll
        for (int k = 0; k < BK; ++k) {
            float av[8], bw[8];
            const float4* ap = reinterpret_cast<const float4*>(&su.m.As[k][ty * 8]);
            const float4* bp = reinterpret_cast<const float4*>(&su.m.Bs[k][tx * 8]);
            float4 a0 = ap[0], a1 = ap[1], b0 = bp[0], b1 = bp[1];
            av[0]=a0.x; av[1]=a0.y; av[2]=a0.z; av[3]=a0.w; av[4]=a1.x; av[5]=a1.y; av[6]=a1.z; av[7]=a1.w;
            bw[0]=b0.x; bw[1]=b0.y; bw[2]=b0.z; bw[3]=b0.w; bw[4]=b1.x; bw[5]=b1.y; bw[6]=b1.z; bw[7]=b1.w;
            #pragma unroll
            for (int i = 0; i < 8; ++i)
                #pragma unroll
                for (int j = 0; j < 8; ++j)
                    acc[i][j] = fmaf(av[i], bw[j], acc[i][j]);
        }
    }

    const bool isv = (n0 < VIS);
    float lpacc[8];
    #pragma unroll
    for (int i = 0; i < 8; ++i) {
        const int row = m0 + ty * 8 + i;
        float s = 0.f;
        #pragma unroll
        for (int j = 0; j < 8; ++j) {
            const int n = n0 + tx * 8 + j;
            float l = acc[i][j] + lb[n];
            float e = eps[(size_t)row * NDIM + n];
            float z = 1.f / (1.f + expf(-(l + e) * 5.f));
            float p = 1.f / (1.f + expf(-l));
            float bb;
            if (isv) { zv[(size_t)row * VIS + n] = z; bb = bv[n]; }
            else     { zh[(size_t)row * HID + (n - VIS)] = z; bb = bh[n - VIS]; }
            s += logf(z * p + (1.f - z) * (1.f - p)) + z * bb;
        }
        lpacc[i] = s;
    }
    __syncthreads();
    #pragma unroll
    for (int i = 0; i < 8; ++i) su.m.red[(ty * 8 + i) * 16 + tx] = lpacc[i];
    __syncthreads();
    if (tid < BM) {
        float s = 0.f;
        #pragma unroll
        for (int x = 0; x < 16; ++x) s += su.m.red[tid * 16 + x];
        atomicAdd(&lp_row[m0 + tid], s);
    }
}

// ---------- GEMM2: fe quadratic term: rowsum((zeta_v @ w) * zeta_h) ----------
__global__ __launch_bounds__(256) void gemm2_fe(
    const float* __restrict__ A, const float* __restrict__ B,
    const float* __restrict__ ZH, float* __restrict__ fe_row)
{
    __shared__ float As[BK][BM];
    __shared__ float Bs[BK][BN];
    __shared__ float red[BM * 16];
    const int tid = threadIdx.x;
    const int n0 = blockIdx.x * BN;
    const int m0 = blockIdx.y * BM;
    const int tx = tid & 15, ty = tid >> 4;
    const int ar = tid >> 1, ac = (tid & 1) * 4;
    const int br = tid >> 5, bc = (tid & 31) * 4;

    float acc[8][8];
    #pragma unroll
    for (int i = 0; i < 8; ++i)
        #pragma unroll
        for (int j = 0; j < 8; ++j) acc[i][j] = 0.f;

    for (int k0 = 0; k0 < 1024; k0 += BK) {
        float4 a = *reinterpret_cast<const float4*>(&A[(size_t)(m0 + ar) * 1024 + k0 + ac]);
        float4 b = *reinterpret_cast<const float4*>(&B[(size_t)(k0 + br) * 1024 + n0 + bc]);
        __syncthreads();
        As[ac + 0][ar] = a.x; As[ac + 1][ar] = a.y; As[ac + 2][ar] = a.z; As[ac + 3][ar] = a.w;
        *reinterpret_cast<float4*>(&Bs[br][bc]) = b;
        __syncthreads();
        #pragma unroll
        for (int k = 0; k < BK; ++k) {
            float av[8], bw[8];
            const float4* ap = reinterpret_cast<const float4*>(&As[k][ty * 8]);
            const float4* bp = reinterpret_cast<const float4*>(&Bs[k][tx * 8]);
            float4 a0 = ap[0], a1 = ap[1], b0 = bp[0], b1 = bp[1];
            av[0]=a0.x; av[1]=a0.y; av[2]=a0.z; av[3]=a0.w; av[4]=a1.x; av[5]=a1.y; av[6]=a1.z; av[7]=a1.w;
            bw[0]=b0.x; bw[1]=b0.y; bw[2]=b0.z; bw[3]=b0.w; bw[4]=b1.x; bw[5]=b1.y; bw[6]=b1.z; bw[7]=b1.w;
            #pragma unroll
            for (int i = 0; i < 8; ++i)
                #pragma unroll
                for (int j = 0; j < 8; ++j)
                    acc[i][j] = fmaf(av[i], bw[j], acc[i][j]);
        }
    }

    float feacc[8];
    #pragma unroll
    for (int i = 0; i < 8; ++i) {
        const int row = m0 + ty * 8 + i;
        float s = 0.f;
        #pragma unroll
        for (int j = 0; j < 8; ++j) {
            const int n = n0 + tx * 8 + j;
            s += acc[i][j] * ZH[(size_t)row * HID + n];
        }
        feacc[i] = s;
    }
    __syncthreads();
    #pragma unroll
    for (int i = 0; i < 8; ++i) red[(ty * 8 + i) * 16 + tx] = feacc[i];
    __syncthreads();
    if (tid < BM) {
        float s = 0.f;
        #pragma unroll
        for (int x = 0; x < 16; ++x) s += red[tid * 16 + x];
        atomicAdd(&fe_row[m0 + tid], s);
    }
}

// ---------- free energy of the 10 samples (f64) ----------
__global__ __launch_bounds__(256) void fe_samples_k(
    const float* __restrict__ w, const float* __restrict__ bv,
    const float* __restrict__ bh, const float* __restrict__ ssv,
    const float* __restrict__ ssh, double* __restrict__ fe_sum)
{
    __shared__ float svl[1024], shl[1024];
    __shared__ double dred[256];
    const int s = blockIdx.x, tid = threadIdx.x;
    for (int m = tid; m < 1024; m += 256) {
        svl[m] = ssv[(size_t)s * 1024 + m];
        shl[m] = ssh[(size_t)s * 1024 + m];
    }
    __syncthreads();
    double acc = 0.0;
    for (int jj = 0; jj < 4; ++jj) {
        int j = tid + jj * 256;
        acc += (double)(svl[j] * bv[j]) + (double)(shl[j] * bh[j]);
        if (shl[j] != 0.f) {
            double y = 0.0;
            for (int i = 0; i < 1024; ++i)
                if (svl[i] != 0.f) y += (double)w[(size_t)i * 1024 + j];
            acc += y;
        }
    }
    dred[tid] = acc;
    __syncthreads();
    for (int off = 128; off > 0; off >>= 1) {
        if (tid < off) dred[tid] += dred[tid + off];
        __syncthreads();
    }
    if (tid == 0) atomicAdd(fe_sum, dred[0]);
}

__global__ __launch_bounds__(256) void final_kl(
    const float* __restrict__ lp_row, const float* __restrict__ fe_row,
    const double* __restrict__ fe_sum, float* __restrict__ out_kl)
{
    __shared__ double dred[256];
    const int tid = threadIdx.x;
    double acc = 0.0;
    for (int r = tid; r < NROW; r += 256)
        acc += (double)lp_row[r] + (double)fe_row[r];
    dred[tid] = acc;
    __syncthreads();
    for (int off = 128; off > 0; off >>= 1) {
        if (tid < off) dred[tid] += dred[tid + off];
        __syncthreads();
    }
    if (tid == 0) out_kl[0] = (float)(dred[0] / 8192.0 - fe_sum[0] / 10.0);
}

extern "C" void kernel_launch(void* const* d_in, const int* in_sizes, int n_in,
                              void* d_out, int out_size, void* d_ws, size_t ws_size,
                              hipStream_t stream)
{
    const float* vecs   = (const float*)d_in[0];
    const float* lw     = (const float*)d_in[1];
    const float* lb     = (const float*)d_in[2];
    const float* w      = (const float*)d_in[3];
    const float* bv     = (const float*)d_in[4];
    const float* bh     = (const float*)d_in[5];
    const float* eps    = (const float*)d_in[6];
    const float* u_init = (const float*)d_in[7];
    const float* u_h    = (const float*)d_in[8];
    const float* u_v    = (const float*)d_in[9];

    float* out    = (float*)d_out;
    float* zv     = out;
    float* zh     = out + (size_t)NROW * VIS;
    float* out_kl = out + (size_t)NROW * 2048;

    char* ws = (char*)d_ws;
    float*        wT     = (float*)(ws + WT_OFF);
    float*        lp_row = (float*)(ws + LP_OFF);
    float*        fe_row = (float*)(ws + FE_OFF);
    double*       fes    = (double*)(ws + FES_OFF);
    unsigned int* pubV   = (unsigned int*)(ws + PUBV_OFF);
    unsigned int* pubH   = (unsigned int*)(ws + PUBH_OFF);
    float*        ssv    = (float*)(ws + SSV_OFF);
    float*        ssh    = (float*)(ws + SSH_OFF);

    const int zwords = (int)(ZERO_BYTES / 4);
    init_zero<<<(zwords + 255) / 256, 256, 0, stream>>>(lp_row, zwords);
    init_words<<<1, 64, 0, stream>>>(u_init, pubV, pubH);
    transpose_w_k<<<dim3(32, 32), 256, 0, stream>>>(w, wT);
    gibbs_gemm1_k<<<NWG + 16 * 64, 256, 0, stream>>>(
        w, wT, bv, bh, u_h, u_v, pubV, pubH, ssv, ssh,
        vecs, lw, lb, eps, zv, zh, lp_row);
    gemm2_fe<<<dim3(8, 64), 256, 0, stream>>>(zv, w, zh, fe_row);
    fe_samples_k<<<KLS, 256, 0, stream>>>(w, bv, bh, ssv, ssh, fes);
    final_kl<<<1, 256, 0, stream>>>(lp_row, fe_row, fes, out_kl);
}

// Round 4
// 14424.719 us; speedup vs baseline: 3.0385x; 2.8705x over previous
//
#include <hip/hip_runtime.h>
#include <math.h>

#define VIS 1024
#define HID 1024
#define NROW 8192
#define KDIM 2048
#define NDIM 2048
#define NSTEPS 2010
#define KLS 10

// ---- ws layout (bytes) ----
#define WT_OFF   0u                      // wT: 1024x1024 f32 (4 MB)
#define LP_OFF   4194304u                // lp_row: 8192 f32
#define FE_OFF   (LP_OFF + 32768u)       // fe_row: 8192 f32
#define FES_OFF  (FE_OFF + 32768u)       // fe_samples sum: 1 double

__global__ __launch_bounds__(256) void init_zero(float* p, int n) {
    int i = blockIdx.x * 256 + threadIdx.x;
    if (i < n) p[i] = 0.f;
}

__global__ __launch_bounds__(256) void transpose_w_k(const float* __restrict__ w,
                                                     float* __restrict__ wT) {
    __shared__ float tile[32][33];
    int bx = blockIdx.x * 32, by = blockIdx.y * 32;
    int tx = threadIdx.x & 31, ty = threadIdx.x >> 5;  // ty 0..7
    #pragma unroll
    for (int m = 0; m < 4; ++m) {
        int y = by + ty + m * 8;
        tile[ty + m * 8][tx] = w[(size_t)y * 1024 + bx + tx];
    }
    __syncthreads();
    #pragma unroll
    for (int m = 0; m < 4; ++m) {
        int y = bx + ty + m * 8;
        wT[(size_t)y * 1024 + by + tx] = tile[tx][ty + m * 8];
    }
}

// ---------------- shared-memory union for the fused kernel ----------------
struct SGibbs {
    unsigned long long HW[16], HF[16], VW[16], VF[16];  // sh / sv masks + flip masks
    double redd[16];
};
struct SMm1 {
    float As[8][136];       // padded: 2-way-max bank aliasing
    float Bs[8][136];
    float red[128 * 33];    // padded reduction buffer (was 32-way conflicted)
};
union SharedU { SGibbs g; SMm1 m; };

// masked delta update: acc += sum over flipped rows h of (+/-) M[h*1024 + j]
// 4-wide manual unroll to keep >=4 loads in flight (masks are wave-uniform).
__device__ __forceinline__ void flip_update(double& acc,
                                            const unsigned long long* SW,
                                            const unsigned long long* FW,
                                            const float* __restrict__ M, int j) {
    for (int u = 0; u < 16; ++u) {
        unsigned long long f = FW[u];
        const unsigned long long s = SW[u];
        const int base = u * 64;
        while (f) {
            int p0 = __ffsll((long long)f) - 1; f &= f - 1;
            bool h1 = f != 0; int p1 = h1 ? __ffsll((long long)f) - 1 : p0; if (h1) f &= f - 1;
            bool h2 = f != 0; int p2 = h2 ? __ffsll((long long)f) - 1 : p0; if (h2) f &= f - 1;
            bool h3 = f != 0; int p3 = h3 ? __ffsll((long long)f) - 1 : p0; if (h3) f &= f - 1;
            double v0 = (double)M[(size_t)(base + p0) * 1024 + j];
            double v1 = (double)M[(size_t)(base + p1) * 1024 + j];
            double v2 = (double)M[(size_t)(base + p2) * 1024 + j];
            double v3 = (double)M[(size_t)(base + p3) * 1024 + j];
            acc += ((s >> p0) & 1) ? v0 : -v0;
            if (h1) acc += ((s >> p1) & 1) ? v1 : -v1;
            if (h2) acc += ((s >> p2) & 1) ? v2 : -v2;
            if (h3) acc += ((s >> p3) & 1) ? v3 : -v3;
        }
    }
}

// ---- fused: block 0 = whole Gibbs chain (1 WG, flip-incremental, f64);
// ----        blocks 1..1024 = GEMM1 + zeta + log-posterior epilogue.
__global__ __launch_bounds__(1024) void fused_k(
    const float* __restrict__ w, const float* __restrict__ wT,
    const float* __restrict__ bv, const float* __restrict__ bh,
    const float* __restrict__ u_init, const float* __restrict__ u_h,
    const float* __restrict__ u_v, double* __restrict__ fes,
    const float* __restrict__ A, const float* __restrict__ B,
    const float* __restrict__ lb, const float* __restrict__ eps,
    float* __restrict__ zv, float* __restrict__ zh, float* __restrict__ lp_row)
{
    __shared__ SharedU su;
    const int tid = threadIdx.x;

    if (blockIdx.x == 0) {
        // ======================= GIBBS (single WG) =======================
        SGibbs& sg = su.g;
        const int j = tid;                // column 0..1023
        const int wv = tid >> 6, lane = tid & 63;
        const double bhj = (double)bh[j], bvj = (double)bv[j];
        double doth = 0.0, dotv = 0.0, fe_acc = 0.0;

        if (tid < 16) sg.HW[tid] = 0ull;            // virtual all-zero sh state
        bool svbit = (u_init[j] >= 0.5f);
        {
            unsigned long long b0 = __ballot(svbit);
            if (lane == 0) { sg.VW[wv] = b0; sg.VF[wv] = b0; }  // flips from zero
        }
        float uh = u_h[j];                           // prefetch u_h[0]
        __syncthreads();
        flip_update(doth, sg.VW, sg.VF, w, j);       // initial doth = sv0 @ w col j

        for (int t = 0; t < NSTEPS; ++t) {
            // ---- phase a: sh = (u >= sigmoid(doth + bh))  [u*(1+e^-y) >= 1] ----
            double e = exp(-(doth + bhj));
            bool shbit = ((double)uh * (1.0 + e) >= 1.0);
            float uv = u_v[(size_t)t * 1024 + j];    // prefetch (used in phase b)
            unsigned long long nb = __ballot(shbit);
            if (lane == 0) {
                unsigned long long old = sg.HW[wv];
                sg.HW[wv] = nb; sg.HF[wv] = nb ^ old;
            }
            __syncthreads();                          // H published
            flip_update(dotv, sg.HW, sg.HF, wT, j);   // dotv tracks sh @ wT

            // ---- phase b: sv2 = (u >= sigmoid(dotv + bv)) ----
            double e2 = exp(-(dotv + bvj));
            bool svb = ((double)uv * (1.0 + e2) >= 1.0);
            if (t + 1 < NSTEPS) uh = u_h[(size_t)(t + 1) * 1024 + j];
            unsigned long long nb2 = __ballot(svb);
            if (lane == 0) {
                unsigned long long old = sg.VW[wv];
                sg.VW[wv] = nb2; sg.VF[wv] = nb2 ^ old;
            }
            __syncthreads();                          // V published
            flip_update(doth, sg.VW, sg.VF, w, j);    // doth tracks sv2 @ w

            // ---- sample free energy: fe = sv2.bv + sh.bh + sum_j sh_j*doth_j ----
            if (t >= NSTEPS - KLS) {
                double c = (svb ? bvj : 0.0) + (shbit ? (bhj + doth) : 0.0);
                #pragma unroll
                for (int o = 32; o > 0; o >>= 1) c += __shfl_down(c, o);
                if (lane == 0) sg.redd[wv] = c;
                __syncthreads();
                if (tid == 0) {
                    double s2 = 0.0;
                    for (int q = 0; q < 16; ++q) s2 += sg.redd[q];
                    fe_acc += s2;
                }
                __syncthreads();
            }
        }
        if (tid == 0) fes[0] = fe_acc;
        return;
    }

    // ======================= GEMM1 (+ zeta + log-posterior) =======================
    const int gid = blockIdx.x - 1;
    const int n0 = (gid & 15) * 128;
    const int m0 = (gid >> 4) * 128;
    const int tx = tid & 31, ty = tid >> 5;       // 32x32 grid of 4x4 microtiles
    const int lr = tid >> 3, lk = tid & 7;        // A-tile load coords
    const int br2 = tid >> 7, bc2 = tid & 127;    // B-tile load coords

    float acc[4][4];
    #pragma unroll
    for (int i = 0; i < 4; ++i)
        #pragma unroll
        for (int jj = 0; jj < 4; ++jj) acc[i][jj] = 0.f;

    float a_reg = A[(size_t)(m0 + lr) * KDIM + lk];
    float b_reg = B[(size_t)br2 * NDIM + n0 + bc2];
    for (int k0 = 0; k0 < KDIM; k0 += 8) {
        __syncthreads();
        su.m.As[lk][lr] = a_reg;
        su.m.Bs[br2][bc2] = b_reg;
        __syncthreads();
        if (k0 + 8 < KDIM) {                        // register prefetch of next tile
            a_reg = A[(size_t)(m0 + lr) * KDIM + (k0 + 8) + lk];
            b_reg = B[(size_t)(k0 + 8 + br2) * NDIM + n0 + bc2];
        }
        #pragma unroll
        for (int k = 0; k < 8; ++k) {
            float4 av = *reinterpret_cast<const float4*>(&su.m.As[k][ty * 4]);
            float4 bw = *reinterpret_cast<const float4*>(&su.m.Bs[k][tx * 4]);
            float aa[4] = {av.x, av.y, av.z, av.w};
            float bb4[4] = {bw.x, bw.y, bw.z, bw.w};
            #pragma unroll
            for (int i = 0; i < 4; ++i)
                #pragma unroll
                for (int jj = 0; jj < 4; ++jj)
                    acc[i][jj] = fmaf(aa[i], bb4[jj], acc[i][jj]);
        }
    }

    const bool isv = (n0 < VIS);
    float lpacc[4];
    #pragma unroll
    for (int i = 0; i < 4; ++i) {
        const int row = m0 + ty * 4 + i;
        float s = 0.f;
        #pragma unroll
        for (int jj = 0; jj < 4; ++jj) {
            const int n = n0 + tx * 4 + jj;
            float l = acc[i][jj] + lb[n];
            float e = eps[(size_t)row * NDIM + n];
            float z = 1.f / (1.f + expf(-(l + e) * 5.f));
            float p = 1.f / (1.f + expf(-l));
            float bb;
            if (isv) { zv[(size_t)row * VIS + n] = z; bb = bv[n]; }
            else     { zh[(size_t)row * HID + (n - VIS)] = z; bb = bh[n - VIS]; }
            s += logf(z * p + (1.f - z) * (1.f - p)) + z * bb;
        }
        lpacc[i] = s;
    }
    __syncthreads();
    #pragma unroll
    for (int i = 0; i < 4; ++i) su.m.red[(ty * 4 + i) * 33 + tx] = lpacc[i];
    __syncthreads();
    if (tid < 128) {
        float s = 0.f;
        #pragma unroll
        for (int x = 0; x < 32; ++x) s += su.m.red[tid * 33 + x];
        atomicAdd(&lp_row[m0 + tid], s);
    }
}

// ---------- GEMM2: fe quadratic term: rowsum((zeta_v @ w) * zeta_h) ----------
#define BM 128
#define BN 128
#define BK 8

__global__ __launch_bounds__(256) void gemm2_fe(
    const float* __restrict__ A, const float* __restrict__ B,
    const float* __restrict__ ZH, float* __restrict__ fe_row)
{
    __shared__ float As[BK][BM];
    __shared__ float Bs[BK][BN];
    __shared__ float red[BM * 17];
    const int tid = threadIdx.x;
    const int n0 = blockIdx.x * BN;
    const int m0 = blockIdx.y * BM;
    const int tx = tid & 15, ty = tid >> 4;
    const int ar = tid >> 1, ac = (tid & 1) * 4;
    const int br = tid >> 5, bc = (tid & 31) * 4;

    float acc[8][8];
    #pragma unroll
    for (int i = 0; i < 8; ++i)
        #pragma unroll
        for (int j = 0; j < 8; ++j) acc[i][j] = 0.f;

    for (int k0 = 0; k0 < 1024; k0 += BK) {
        float4 a = *reinterpret_cast<const float4*>(&A[(size_t)(m0 + ar) * 1024 + k0 + ac]);
        float4 b = *reinterpret_cast<const float4*>(&B[(size_t)(k0 + br) * 1024 + n0 + bc]);
        __syncthreads();
        As[ac + 0][ar] = a.x; As[ac + 1][ar] = a.y; As[ac + 2][ar] = a.z; As[ac + 3][ar] = a.w;
        *reinterpret_cast<float4*>(&Bs[br][bc]) = b;
        __syncthreads();
        #pragma unroll
        for (int k = 0; k < BK; ++k) {
            float av[8], bw[8];
            const float4* ap = reinterpret_cast<const float4*>(&As[k][ty * 8]);
            const float4* bp = reinterpret_cast<const float4*>(&Bs[k][tx * 8]);
            float4 a0 = ap[0], a1 = ap[1], b0 = bp[0], b1 = bp[1];
            av[0]=a0.x; av[1]=a0.y; av[2]=a0.z; av[3]=a0.w; av[4]=a1.x; av[5]=a1.y; av[6]=a1.z; av[7]=a1.w;
            bw[0]=b0.x; bw[1]=b0.y; bw[2]=b0.z; bw[3]=b0.w; bw[4]=b1.x; bw[5]=b1.y; bw[6]=b1.z; bw[7]=b1.w;
            #pragma unroll
            for (int i = 0; i < 8; ++i)
                #pragma unroll
                for (int j = 0; j < 8; ++j)
                    acc[i][j] = fmaf(av[i], bw[j], acc[i][j]);
        }
    }

    float feacc[8];
    #pragma unroll
    for (int i = 0; i < 8; ++i) {
        const int row = m0 + ty * 8 + i;
        float s = 0.f;
        #pragma unroll
        for (int j = 0; j < 8; ++j) {
            const int n = n0 + tx * 8 + j;
            s += acc[i][j] * ZH[(size_t)row * HID + n];
        }
        feacc[i] = s;
    }
    __syncthreads();
    #pragma unroll
    for (int i = 0; i < 8; ++i) red[(ty * 8 + i) * 17 + tx] = feacc[i];
    __syncthreads();
    if (tid < BM) {
        float s = 0.f;
        #pragma unroll
        for (int x = 0; x < 16; ++x) s += red[tid * 17 + x];
        atomicAdd(&fe_row[m0 + tid], s);
    }
}

__global__ __launch_bounds__(256) void final_kl(
    const float* __restrict__ lp_row, const float* __restrict__ fe_row,
    const double* __restrict__ fe_sum, float* __restrict__ out_kl)
{
    __shared__ double dred[256];
    const int tid = threadIdx.x;
    double acc = 0.0;
    for (int r = tid; r < NROW; r += 256)
        acc += (double)lp_row[r] + (double)fe_row[r];
    dred[tid] = acc;
    __syncthreads();
    for (int off = 128; off > 0; off >>= 1) {
        if (tid < off) dred[tid] += dred[tid + off];
        __syncthreads();
    }
    if (tid == 0) out_kl[0] = (float)(dred[0] / 8192.0 - fe_sum[0] / 10.0);
}

extern "C" void kernel_launch(void* const* d_in, const int* in_sizes, int n_in,
                              void* d_out, int out_size, void* d_ws, size_t ws_size,
                              hipStream_t stream)
{
    const float* vecs   = (const float*)d_in[0];
    const float* lw     = (const float*)d_in[1];
    const float* lb     = (const float*)d_in[2];
    const float* w      = (const float*)d_in[3];
    const float* bv     = (const float*)d_in[4];
    const float* bh     = (const float*)d_in[5];
    const float* eps    = (const float*)d_in[6];
    const float* u_init = (const float*)d_in[7];
    const float* u_h    = (const float*)d_in[8];
    const float* u_v    = (const float*)d_in[9];

    float* out    = (float*)d_out;
    float* zv     = out;
    float* zh     = out + (size_t)NROW * VIS;
    float* out_kl = out + (size_t)NROW * 2048;

    char* ws = (char*)d_ws;
    float*  wT     = (float*)(ws + WT_OFF);
    float*  lp_row = (float*)(ws + LP_OFF);
    float*  fe_row = (float*)(ws + FE_OFF);
    double* fes    = (double*)(ws + FES_OFF);

    init_zero<<<64, 256, 0, stream>>>(lp_row, 16384);   // lp_row + fe_row
    transpose_w_k<<<dim3(32, 32), 256, 0, stream>>>(w, wT);
    fused_k<<<1 + 1024, 1024, 0, stream>>>(
        w, wT, bv, bh, u_init, u_h, u_v, fes,
        vecs, lw, lb, eps, zv, zh, lp_row);
    gemm2_fe<<<dim3(8, 64), 256, 0, stream>>>(zv, w, zh, fe_row);
    final_kl<<<1, 256, 0, stream>>>(lp_row, fe_row, fes, out_kl);
}

// Round 5
// 11944.685 us; speedup vs baseline: 3.6693x; 1.2076x over previous
//
#include <hip/hip_runtime.h>
#include <math.h>

#define VIS 1024
#define HID 1024
#define NROW 8192
#define KDIM 2048
#define NDIM 2048
#define NSTEPS 2010
#define KLS 10

// ---- ws layout (bytes) ----
#define WT_OFF   0u                      // wT: 1024x1024 f32 (4 MB)
#define LP_OFF   4194304u                // lp_row: 8192 f32
#define FE_OFF   (LP_OFF + 32768u)       // fe_row: 8192 f32
#define FES_OFF  (FE_OFF + 32768u)       // fe_samples sum: 1 double

__global__ __launch_bounds__(256) void init_zero(float* p, int n) {
    int i = blockIdx.x * 256 + threadIdx.x;
    if (i < n) p[i] = 0.f;
}

__global__ __launch_bounds__(256) void transpose_w_k(const float* __restrict__ w,
                                                     float* __restrict__ wT) {
    __shared__ float tile[32][33];
    int bx = blockIdx.x * 32, by = blockIdx.y * 32;
    int tx = threadIdx.x & 31, ty = threadIdx.x >> 5;  // ty 0..7
    #pragma unroll
    for (int m = 0; m < 4; ++m) {
        int y = by + ty + m * 8;
        tile[ty + m * 8][tx] = w[(size_t)y * 1024 + bx + tx];
    }
    __syncthreads();
    #pragma unroll
    for (int m = 0; m < 4; ++m) {
        int y = bx + ty + m * 8;
        wT[(size_t)y * 1024 + by + tx] = tile[tx][ty + m * 8];
    }
}

// ---------------- shared-memory union for the fused kernel ----------------
struct SGibbs {
    unsigned long long HW[16], HF[16], VW[16], VF[16];  // state masks + flip masks
    double redd[16];
    int sidx[1024];      // linearized flip list: (row<<1)|signbit
    int nflip;
};
struct SMm1 {
    float As[8][136];
    float Bs[8][136];
    float red[128 * 33];
};
union SharedU { SGibbs g; SMm1 m; };

// 16 threads expand the 16 flip words into a linear LDS list (offset = prefix popcount).
__device__ __forceinline__ void expand_flips(const unsigned long long* __restrict__ W,
                                             const unsigned long long* __restrict__ F,
                                             int* __restrict__ sidx, int* __restrict__ nflip,
                                             int tid) {
    if (tid < 16) {
        int off = 0;
        #pragma unroll
        for (int u = 0; u < 16; ++u)
            if (u < tid) off += __popcll(F[u]);
        unsigned long long f = F[tid];
        const unsigned long long s = W[tid];
        int k = off;
        while (f) {
            int p = __ffsll((long long)f) - 1;
            f &= f - 1;
            sidx[k++] = (((tid << 6) + p) << 1) | (int)((s >> p) & 1);
        }
        if (tid == 15) *nflip = k;
    }
}

// flat flip-apply: all loads independent -> one latency window, 8 in flight.
__device__ __forceinline__ void apply_flips(double& acc, const int* __restrict__ sidx,
                                            int n, const float* __restrict__ M, int j) {
    int i = 0;
    for (; i + 8 <= n; i += 8) {
        int e0 = sidx[i    ], e1 = sidx[i + 1], e2 = sidx[i + 2], e3 = sidx[i + 3];
        int e4 = sidx[i + 4], e5 = sidx[i + 5], e6 = sidx[i + 6], e7 = sidx[i + 7];
        float v0 = M[(size_t)(e0 >> 1) * 1024 + j];
        float v1 = M[(size_t)(e1 >> 1) * 1024 + j];
        float v2 = M[(size_t)(e2 >> 1) * 1024 + j];
        float v3 = M[(size_t)(e3 >> 1) * 1024 + j];
        float v4 = M[(size_t)(e4 >> 1) * 1024 + j];
        float v5 = M[(size_t)(e5 >> 1) * 1024 + j];
        float v6 = M[(size_t)(e6 >> 1) * 1024 + j];
        float v7 = M[(size_t)(e7 >> 1) * 1024 + j];
        acc += (e0 & 1) ? (double)v0 : -(double)v0;
        acc += (e1 & 1) ? (double)v1 : -(double)v1;
        acc += (e2 & 1) ? (double)v2 : -(double)v2;
        acc += (e3 & 1) ? (double)v3 : -(double)v3;
        acc += (e4 & 1) ? (double)v4 : -(double)v4;
        acc += (e5 & 1) ? (double)v5 : -(double)v5;
        acc += (e6 & 1) ? (double)v6 : -(double)v6;
        acc += (e7 & 1) ? (double)v7 : -(double)v7;
    }
    for (; i < n; ++i) {
        int e = sidx[i];
        float v = M[(size_t)(e >> 1) * 1024 + j];
        acc += (e & 1) ? (double)v : -(double)v;
    }
}

// ---- fused: block 0 = whole Gibbs chain (1 WG, flip-incremental, f64);
// ----        blocks 1..1024 = GEMM1 + zeta + log-posterior epilogue.
__global__ __launch_bounds__(1024) void fused_k(
    const float* __restrict__ w, const float* __restrict__ wT,
    const float* __restrict__ bv, const float* __restrict__ bh,
    const float* __restrict__ u_init, const float* __restrict__ u_h,
    const float* __restrict__ u_v, double* __restrict__ fes,
    const float* __restrict__ A, const float* __restrict__ B,
    const float* __restrict__ lb, const float* __restrict__ eps,
    float* __restrict__ zv, float* __restrict__ zh, float* __restrict__ lp_row)
{
    __shared__ SharedU su;
    const int tid = threadIdx.x;

    if (blockIdx.x == 0) {
        // ======================= GIBBS (single WG) =======================
        SGibbs& sg = su.g;
        const int j = tid;                // column 0..1023
        const int wv = tid >> 6, lane = tid & 63;
        const double bhj = (double)bh[j], bvj = (double)bv[j];
        double doth = 0.0, dotv = 0.0, fe_acc = 0.0;

        if (tid < 16) sg.HW[tid] = 0ull;            // virtual all-zero sh state
        bool svbit = (u_init[j] >= 0.5f);
        {
            unsigned long long b0 = __ballot(svbit);
            if (lane == 0) { sg.VW[wv] = b0; sg.VF[wv] = b0; }  // flips from zero
        }
        // decision form: u >= sigmoid(y) <=> y <= logit(u), y = dot + b
        double uh0 = (double)u_h[j];
        double thr_h = log(uh0) - log1p(-uh0) - bhj;
        float uv_pf = u_v[j];
        __syncthreads();
        expand_flips(sg.VW, sg.VF, sg.sidx, &sg.nflip, tid);
        __syncthreads();
        apply_flips(doth, sg.sidx, sg.nflip, w, j);   // doth = sv0 @ w col j

        for (int t = 0; t < NSTEPS; ++t) {
            // ---- phase a: sh = (doth <= thr_h) ----
            bool shbit = (doth <= thr_h);
            unsigned long long nb = __ballot(shbit);
            if (lane == 0) {
                unsigned long long old = sg.HW[wv];
                sg.HW[wv] = nb; sg.HF[wv] = nb ^ old;
            }
            double uvd = (double)uv_pf;                       // overlap: next threshold
            double thr_v = log(uvd) - log1p(-uvd) - bvj;
            float uh_pf = (t + 1 < NSTEPS) ? u_h[(size_t)(t + 1) * 1024 + j] : 0.5f;
            __syncthreads();                                  // masks published
            expand_flips(sg.HW, sg.HF, sg.sidx, &sg.nflip, tid);
            __syncthreads();                                  // flip list ready
            apply_flips(dotv, sg.sidx, sg.nflip, wT, j);      // dotv tracks sh @ wT

            // ---- phase b: sv2 = (dotv <= thr_v) ----
            bool svb = (dotv <= thr_v);
            unsigned long long nb2 = __ballot(svb);
            if (lane == 0) {
                unsigned long long old = sg.VW[wv];
                sg.VW[wv] = nb2; sg.VF[wv] = nb2 ^ old;
            }
            double uhd = (double)uh_pf;
            thr_h = log(uhd) - log1p(-uhd) - bhj;
            if (t + 1 < NSTEPS) uv_pf = u_v[(size_t)(t + 1) * 1024 + j];
            __syncthreads();                                  // masks published
            expand_flips(sg.VW, sg.VF, sg.sidx, &sg.nflip, tid);
            __syncthreads();                                  // flip list ready
            apply_flips(doth, sg.sidx, sg.nflip, w, j);       // doth tracks sv2 @ w

            // ---- sample free energy: fe = sv2.bv + sh.bh + sum_j sh_j*doth_j ----
            if (t >= NSTEPS - KLS) {
                double c = (svb ? bvj : 0.0) + (shbit ? (bhj + doth) : 0.0);
                #pragma unroll
                for (int o = 32; o > 0; o >>= 1) c += __shfl_down(c, o);
                if (lane == 0) sg.redd[wv] = c;
                __syncthreads();
                if (tid == 0) {
                    double s2 = 0.0;
                    for (int q = 0; q < 16; ++q) s2 += sg.redd[q];
                    fe_acc += s2;
                }
                __syncthreads();
            }
        }
        if (tid == 0) fes[0] = fe_acc;
        return;
    }

    // ======================= GEMM1 (+ zeta + log-posterior) =======================
    const int gid = blockIdx.x - 1;
    const int n0 = (gid & 15) * 128;
    const int m0 = (gid >> 4) * 128;
    const int tx = tid & 31, ty = tid >> 5;       // 32x32 grid of 4x4 microtiles
    const int lr = tid >> 3, lk = tid & 7;        // A-tile load coords
    const int br2 = tid >> 7, bc2 = tid & 127;    // B-tile load coords

    float acc[4][4];
    #pragma unroll
    for (int i = 0; i < 4; ++i)
        #pragma unroll
        for (int jj = 0; jj < 4; ++jj) acc[i][jj] = 0.f;

    float a_reg = A[(size_t)(m0 + lr) * KDIM + lk];
    float b_reg = B[(size_t)br2 * NDIM + n0 + bc2];
    for (int k0 = 0; k0 < KDIM; k0 += 8) {
        __syncthreads();
        su.m.As[lk][lr] = a_reg;
        su.m.Bs[br2][bc2] = b_reg;
        __syncthreads();
        if (k0 + 8 < KDIM) {                        // register prefetch of next tile
            a_reg = A[(size_t)(m0 + lr) * KDIM + (k0 + 8) + lk];
            b_reg = B[(size_t)(k0 + 8 + br2) * NDIM + n0 + bc2];
        }
        #pragma unroll
        for (int k = 0; k < 8; ++k) {
            float4 av = *reinterpret_cast<const float4*>(&su.m.As[k][ty * 4]);
            float4 bw = *reinterpret_cast<const float4*>(&su.m.Bs[k][tx * 4]);
            float aa[4] = {av.x, av.y, av.z, av.w};
            float bb4[4] = {bw.x, bw.y, bw.z, bw.w};
            #pragma unroll
            for (int i = 0; i < 4; ++i)
                #pragma unroll
                for (int jj = 0; jj < 4; ++jj)
                    acc[i][jj] = fmaf(aa[i], bb4[jj], acc[i][jj]);
        }
    }

    const bool isv = (n0 < VIS);
    float lpacc[4];
    #pragma unroll
    for (int i = 0; i < 4; ++i) {
        const int row = m0 + ty * 4 + i;
        float s = 0.f;
        #pragma unroll
        for (int jj = 0; jj < 4; ++jj) {
            const int n = n0 + tx * 4 + jj;
            float l = acc[i][jj] + lb[n];
            float e = eps[(size_t)row * NDIM + n];
            float z = 1.f / (1.f + expf(-(l + e) * 5.f));
            float p = 1.f / (1.f + expf(-l));
            float bb;
            if (isv) { zv[(size_t)row * VIS + n] = z; bb = bv[n]; }
            else     { zh[(size_t)row * HID + (n - VIS)] = z; bb = bh[n - VIS]; }
            s += logf(z * p + (1.f - z) * (1.f - p)) + z * bb;
        }
        lpacc[i] = s;
    }
    __syncthreads();
    #pragma unroll
    for (int i = 0; i < 4; ++i) su.m.red[(ty * 4 + i) * 33 + tx] = lpacc[i];
    __syncthreads();
    if (tid < 128) {
        float s = 0.f;
        #pragma unroll
        for (int x = 0; x < 32; ++x) s += su.m.red[tid * 33 + x];
        atomicAdd(&lp_row[m0 + tid], s);
    }
}

// ---------- GEMM2: fe quadratic term: rowsum((zeta_v @ w) * zeta_h) ----------
#define BM 128
#define BN 128
#define BK 8

__global__ __launch_bounds__(256) void gemm2_fe(
    const float* __restrict__ A, const float* __restrict__ B,
    const float* __restrict__ ZH, float* __restrict__ fe_row)
{
    __shared__ float As[BK][BM];
    __shared__ float Bs[BK][BN];
    __shared__ float red[BM * 17];
    const int tid = threadIdx.x;
    const int n0 = blockIdx.x * BN;
    const int m0 = blockIdx.y * BM;
    const int tx = tid & 15, ty = tid >> 4;
    const int ar = tid >> 1, ac = (tid & 1) * 4;
    const int br = tid >> 5, bc = (tid & 31) * 4;

    float acc[8][8];
    #pragma unroll
    for (int i = 0; i < 8; ++i)
        #pragma unroll
        for (int j = 0; j < 8; ++j) acc[i][j] = 0.f;

    for (int k0 = 0; k0 < 1024; k0 += BK) {
        float4 a = *reinterpret_cast<const float4*>(&A[(size_t)(m0 + ar) * 1024 + k0 + ac]);
        float4 b = *reinterpret_cast<const float4*>(&B[(size_t)(k0 + br) * 1024 + n0 + bc]);
        __syncthreads();
        As[ac + 0][ar] = a.x; As[ac + 1][ar] = a.y; As[ac + 2][ar] = a.z; As[ac + 3][ar] = a.w;
        *reinterpret_cast<float4*>(&Bs[br][bc]) = b;
        __syncthreads();
        #pragma unroll
        for (int k = 0; k < BK; ++k) {
            float av[8], bw[8];
            const float4* ap = reinterpret_cast<const float4*>(&As[k][ty * 8]);
            const float4* bp = reinterpret_cast<const float4*>(&Bs[k][tx * 8]);
            float4 a0 = ap[0], a1 = ap[1], b0 = bp[0], b1 = bp[1];
            av[0]=a0.x; av[1]=a0.y; av[2]=a0.z; av[3]=a0.w; av[4]=a1.x; av[5]=a1.y; av[6]=a1.z; av[7]=a1.w;
            bw[0]=b0.x; bw[1]=b0.y; bw[2]=b0.z; bw[3]=b0.w; bw[4]=b1.x; bw[5]=b1.y; bw[6]=b1.z; bw[7]=b1.w;
            #pragma unroll
            for (int i = 0; i < 8; ++i)
                #pragma unroll
                for (int j = 0; j < 8; ++j)
                    acc[i][j] = fmaf(av[i], bw[j], acc[i][j]);
        }
    }

    float feacc[8];
    #pragma unroll
    for (int i = 0; i < 8; ++i) {
        const int row = m0 + ty * 8 + i;
        float s = 0.f;
        #pragma unroll
        for (int j = 0; j < 8; ++j) {
            const int n = n0 + tx * 8 + j;
            s += acc[i][j] * ZH[(size_t)row * HID + n];
        }
        feacc[i] = s;
    }
    __syncthreads();
    #pragma unroll
    for (int i = 0; i < 8; ++i) red[(ty * 8 + i) * 17 + tx] = feacc[i];
    __syncthreads();
    if (tid < BM) {
        float s = 0.f;
        #pragma unroll
        for (int x = 0; x < 16; ++x) s += red[tid * 17 + x];
        atomicAdd(&fe_row[m0 + tid], s);
    }
}

__global__ __launch_bounds__(256) void final_kl(
    const float* __restrict__ lp_row, const float* __restrict__ fe_row,
    const double* __restrict__ fe_sum, float* __restrict__ out_kl)
{
    __shared__ double dred[256];
    const int tid = threadIdx.x;
    double acc = 0.0;
    for (int r = tid; r < NROW; r += 256)
        acc += (double)lp_row[r] + (double)fe_row[r];
    dred[tid] = acc;
    __syncthreads();
    for (int off = 128; off > 0; off >>= 1) {
        if (tid < off) dred[tid] += dred[tid + off];
        __syncthreads();
    }
    if (tid == 0) out_kl[0] = (float)(dred[0] / 8192.0 - fe_sum[0] / 10.0);
}

extern "C" void kernel_launch(void* const* d_in, const int* in_sizes, int n_in,
                              void* d_out, int out_size, void* d_ws, size_t ws_size,
                              hipStream_t stream)
{
    const float* vecs   = (const float*)d_in[0];
    const float* lw     = (const float*)d_in[1];
    const float* lb     = (const float*)d_in[2];
    const float* w      = (const float*)d_in[3];
    const float* bv     = (const float*)d_in[4];
    const float* bh     = (const float*)d_in[5];
    const float* eps    = (const float*)d_in[6];
    const float* u_init = (const float*)d_in[7];
    const float* u_h    = (const float*)d_in[8];
    const float* u_v    = (const float*)d_in[9];

    float* out    = (float*)d_out;
    float* zv     = out;
    float* zh     = out + (size_t)NROW * VIS;
    float* out_kl = out + (size_t)NROW * 2048;

    char* ws = (char*)d_ws;
    float*  wT     = (float*)(ws + WT_OFF);
    float*  lp_row = (float*)(ws + LP_OFF);
    float*  fe_row = (float*)(ws + FE_OFF);
    double* fes    = (double*)(ws + FES_OFF);

    init_zero<<<64, 256, 0, stream>>>(lp_row, 16384);   // lp_row + fe_row
    transpose_w_k<<<dim3(32, 32), 256, 0, stream>>>(w, wT);
    fused_k<<<1 + 1024, 1024, 0, stream>>>(
        w, wT, bv, bh, u_init, u_h, u_v, fes,
        vecs, lw, lb, eps, zv, zh, lp_row);
    gemm2_fe<<<dim3(8, 64), 256, 0, stream>>>(zv, w, zh, fe_row);
    final_kl<<<1, 256, 0, stream>>>(lp_row, fe_row, fes, out_kl);
}